// Round 10
// baseline (713.236 us; speedup 1.0000x reference)
//
#include <hip/hip_runtime.h>
#include <math.h>

// VectorQuantizer: x (32768,64) f32, codebook (8192,64) f32, start/end/use_sk ints.
// Outputs concat: x_q_st (2097152 f32) | loss (1 f32) | indices (32768 as f32 values).
//
// R10: bf16-MFMA filter emits per-(token, 2048-code block) CANDIDATE RECORDS
// (count + up to 14 u16 codes, 32 B, coalesced); rescue evaluates only those
// candidates with the BIT-EXACT R1 numpy-replica arithmetic.
//  vq_sc:   sc_k exact (pairwise-8 numpy replica, f32) + cb -> cbf_ext rows
//           [c0..c63, bf16(sc_k), 0*15] (K padded 64->80; sc folded via x-ext -0.5).
//  vq_pass1: 32x32x16 MFMA, block = 256 tokens x 2048 codes (16 iters of 128).
//           Per token: running block-max in acc space; after updating it each iter,
//           append codes with acc >= runmax - W/2 to an LDS list; final 32 B record.
//           Superset: needed codes (g <= gmin_global + W) have acc >= globalmax - W/2
//           >= runmax_then - W/2, so they are always appended. Overflow (cnt>14):
//           rescue scans that whole block exactly (rare, still exact).
//  vq_rescue: wave/token. Read 4 records (128 B); lane=(block,slot) evaluates its
//           candidate straight from global cb with the BIT-EXACT R1 arithmetic
//           (pairwise-8, separate mul+add); lex-min (enc(d),k) == strict-<
//           ascending-k first-occurrence. Epilogue fused.
// Error budget (W=3e-4 in g-space, AWIN=W/2 in acc space): bf16 dot err <=6.2e-5 +
// ref d-slop 1.5e-5 ~= 8e-5 < 1.5e-4 (no f16 quantization anymore -> more margin
// than the R5-R9 validated config). DO NOT change the exact-path arithmetic.

#define N_E    8192
#define EDIM   64
#define NTOK   32768
#define NELEM  (NTOK * EDIM)
#define WINDOW 3e-4f
#define AWIN   1.5e-4f             // WINDOW/2 in acc space (g = -2*acc)
#define KEXT   80                  // padded K (64 data + sc-fold + zeros)
#define TTOK   256                 // pass-1 tokens per block
#define TCODE  2048                // pass-1 codes per block (16 iters of 128)
#define SROW   88                  // LDS row stride (ushorts; 44 dwords == 4 mod 8)
#define SLOTS  14                  // candidate slots per (token, block) record

typedef __attribute__((ext_vector_type(8)))  short          short8;
typedef __attribute__((ext_vector_type(8)))  unsigned short ushort8v;
typedef __attribute__((ext_vector_type(4)))  unsigned short ushort4v;
typedef __attribute__((ext_vector_type(16))) float          f32x16;

__device__ __forceinline__ unsigned short f2bf(float f) {   // RTNE f32->bf16 bits
  unsigned int u = __float_as_uint(f);
  return (unsigned short)((u + 0x7FFFu + ((u >> 16) & 1u)) >> 16);
}

// BIT-EXACT R1 numpy-replica distance eval (validated absmax 0.0 since R1).
// DO NOT reorder: products rounded separately, 8 stride-8 accumulators,
// combine ((t0+t1)+(t2+t3))+((t4+t5)+(t6+t7)), d = fl(fl(sx+sc)-2*tt).
__device__ __forceinline__ unsigned long long vq_eval_pack(
    const float* __restrict__ cb, int k, const float4* __restrict__ xl4,
    float sx, const float* __restrict__ sc) {
#pragma clang fp contract(off)
  const float4* c4 = (const float4*)(cb + (size_t)k * EDIM);
  float t[8];
#pragma unroll
  for (int j = 0; j < 8; ++j) t[j] = 0.0f;
#pragma unroll
  for (int i = 0; i < 8; ++i) {              // elements 8i..8i+7, i ascending
    float4 cA4 = c4[2*i], cB4 = c4[2*i+1];
    float4 pA = xl4[2*i], pB = xl4[2*i+1];
    t[0] += cA4.x * pA.x; t[1] += cA4.y * pA.y;
    t[2] += cA4.z * pA.z; t[3] += cA4.w * pA.w;
    t[4] += cB4.x * pB.x; t[5] += cB4.y * pB.y;
    t[6] += cB4.z * pB.z; t[7] += cB4.w * pB.w;
  }
  float tt = ((t[0]+t[1]) + (t[2]+t[3])) + ((t[4]+t[5]) + (t[6]+t[7]));
  float d = (sx + sc[k]) - 2.0f * tt;
  unsigned int db = __float_as_uint(d);
  unsigned int en = db ^ ((unsigned int)((int)db >> 31) | 0x80000000u);
  return ((unsigned long long)en << 32) | (unsigned int)k;
}

// ---------------- sc (exact pairwise-8) + cb -> bf16 ext rows [c, sc, zeros] ---------
__global__ __launch_bounds__(256) void vq_sc(const float* __restrict__ cb,
                                             float* __restrict__ sc,
                                             unsigned short* __restrict__ cbf) {
#pragma clang fp contract(off)
  int r = blockIdx.x * 256 + threadIdx.x;
  const float4* c4 = (const float4*)(cb + (size_t)r * EDIM);
  float a[8];
#pragma unroll
  for (int j = 0; j < 8; ++j) a[j] = 0.0f;
#pragma unroll
  for (int i = 0; i < 8; ++i) {
    float4 pA = c4[2*i], pB = c4[2*i+1];
    a[0] += pA.x * pA.x; a[1] += pA.y * pA.y; a[2] += pA.z * pA.z; a[3] += pA.w * pA.w;
    a[4] += pB.x * pB.x; a[5] += pB.y * pB.y; a[6] += pB.z * pB.z; a[7] += pB.w * pB.w;
  }
  float sval = ((a[0]+a[1]) + (a[2]+a[3])) + ((a[4]+a[5]) + (a[6]+a[7]));
  sc[r] = sval;
  unsigned short* dst = cbf + (size_t)r * KEXT;
#pragma unroll
  for (int h = 0; h < 8; ++h) {
    float4 fA = c4[2*h], fB = c4[2*h+1];
    ushort8v o = {f2bf(fA.x), f2bf(fA.y), f2bf(fA.z), f2bf(fA.w),
                  f2bf(fB.x), f2bf(fB.y), f2bf(fB.z), f2bf(fB.w)};
    *(ushort8v*)&dst[h * 8] = o;
  }
  ushort8v t0 = {0,0,0,0,0,0,0,0};
  t0[0] = f2bf(sval);
  *(ushort8v*)&dst[64] = t0;
  ushort8v z = {0,0,0,0,0,0,0,0};
  *(ushort8v*)&dst[72] = z;
}

// ---------------- pass 1: 32x32x16 MFMA filter -> per-block candidate records --------
// Frags: A[m=lane&31][k=8*(lane>>5)+j] (codes), B same (tokens),
// D: col=lane&31 (token), row=(reg&3)+8*(reg>>2)+4*(lane>>5) (code).
__global__ __launch_bounds__(256, 2) void vq_pass1(
    const float* __restrict__ x, const unsigned short* __restrict__ cbf,
    unsigned int* __restrict__ cand,
    const int* __restrict__ p_start, const int* __restrict__ p_end) {
  __shared__ unsigned short Xs[TTOK * SROW];   // 45056 B
  __shared__ unsigned short Cs[128 * SROW];    // 22528 B
  __shared__ unsigned short cl[TTOK][16];      // 8192 B candidate lists
  int tid = threadIdx.x;
  int tb = blockIdx.x;    // token split [0,128)
  int cbk = blockIdx.y;   // code split  [0,4)
  int s = *p_start, e = *p_end;

  // ---- stage x tile (fused f32 -> bf16-ext conversion) ----
  const float4* xg = (const float4*)(x + (size_t)tb * TTOK * EDIM);
#pragma unroll
  for (int p = 0; p < 16; ++p) {
    int idx = tid + p * 256;                   // [0,4096): row*16 + c4
    int row = idx >> 4, c4i = idx & 15;
    float4 f = xg[idx];
    ushort4v o = {f2bf(f.x), f2bf(f.y), f2bf(f.z), f2bf(f.w)};
    *(ushort4v*)&Xs[row * SROW + c4i * 4] = o;
  }
  {                                            // tail cols 64..79: [-0.5, zeros]
    ushort8v t0 = {0,0,0,0,0,0,0,0};
    t0[0] = f2bf(-0.5f);
    ushort8v z = {0,0,0,0,0,0,0,0};
    *(ushort8v*)&Xs[tid * SROW + 64] = t0;
    *(ushort8v*)&Xs[tid * SROW + 72] = z;
  }
  // ---- stage first code tile: 128 rows x 10 ushort8 = 1280 ----
  const ushort8v* cg0 = (const ushort8v*)(cbf + (size_t)cbk * TCODE * KEXT);
#pragma unroll
  for (int p = 0; p < 5; ++p) {
    int idx = tid + p * 256;
    int row = idx / 10, h = idx % 10;
    *(ushort8v*)&Cs[row * SROW + h * 8] = cg0[idx];
  }
  __syncthreads();

  int lane = tid & 63, wv = tid >> 6;
  int half = lane >> 5, ln = lane & 31;
  int tokbase = wv * 64;
  short8 bfr[2][5];
#pragma unroll
  for (int tg = 0; tg < 2; ++tg)
#pragma unroll
    for (int ks = 0; ks < 5; ++ks)
      bfr[tg][ks] = *(const short8*)&Xs[(tokbase + tg*32 + ln) * SROW + ks*16 + half*8];

  float runmax[2] = {-INFINITY, -INFINITY};
  int cnt = 0;

  for (int nb = 0; nb < 16; ++nb) {
    ushort8v creg[5];
    if (nb < 15) {
      const ushort8v* cg =
          (const ushort8v*)(cbf + ((size_t)cbk * TCODE + (nb + 1) * 128) * KEXT);
#pragma unroll
      for (int p = 0; p < 5; ++p) creg[p] = cg[tid + p * 256];
    }
    f32x16 acc[2][4];
#pragma unroll
    for (int tg = 0; tg < 2; ++tg)
#pragma unroll
      for (int ct = 0; ct < 4; ++ct) acc[tg][ct] = (f32x16)0.0f;
#pragma unroll
    for (int ks = 0; ks < 5; ++ks)
#pragma unroll
      for (int ct = 0; ct < 4; ++ct) {
        short8 a = *(const short8*)&Cs[(ct*32 + ln) * SROW + ks*16 + half*8];
        acc[0][ct] = __builtin_amdgcn_mfma_f32_32x32x16_bf16(a, bfr[0][ks],
                                                             acc[0][ct], 0, 0, 0);
        acc[1][ct] = __builtin_amdgcn_mfma_f32_32x32x16_bf16(a, bfr[1][ks],
                                                             acc[1][ct], 0, 0, 0);
      }
    __syncthreads();                           // all Cs reads done
    if (nb < 15) {
#pragma unroll
      for (int p = 0; p < 5; ++p) {
        int idx = tid + p * 256;
        int row = idx / 10, h = idx % 10;
        *(ushort8v*)&Cs[row * SROW + h * 8] = creg[p];
      }
    }
    // ---- epilogue (registers only; overlaps LDS writes) ----
    int cbase0 = cbk * TCODE + nb * 128;
    bool full = (cbase0 >= s) && (cbase0 + 128 <= e);
    float rm0 = -INFINITY, rm1 = -INFINITY;
    if (full) {
#pragma unroll
      for (int ct = 0; ct < 4; ++ct)
#pragma unroll
        for (int r = 0; r < 16; ++r) {
          rm0 = fmaxf(rm0, acc[0][ct][r]);
          rm1 = fmaxf(rm1, acc[1][ct][r]);
        }
    } else {
#pragma unroll
      for (int ct = 0; ct < 4; ++ct)
#pragma unroll
        for (int r = 0; r < 16; ++r) {
          int code = cbase0 + ct * 32 + (r & 3) + 8 * (r >> 2) + 4 * half;
          if (code >= s && code < e) {
            rm0 = fmaxf(rm0, acc[0][ct][r]);
            rm1 = fmaxf(rm1, acc[1][ct][r]);
          }
        }
    }
    rm0 = fmaxf(rm0, __shfl_xor(rm0, 32, 64));
    rm1 = fmaxf(rm1, __shfl_xor(rm1, 32, 64));
    runmax[0] = fmaxf(runmax[0], rm0);
    runmax[1] = fmaxf(runmax[1], rm1);
    float t0 = runmax[0] - AWIN, t1 = runmax[1] - AWIN;
#pragma unroll
    for (int ct = 0; ct < 4; ++ct) {
      int c0 = cbase0 + ct * 32;
      unsigned b0 = 0, b1 = 0;
      if (full) {
#pragma unroll
        for (int r = 0; r < 16; ++r) {
          int pos = (r & 3) + 8 * (r >> 2) + 4 * half;
          if (acc[0][ct][r] >= t0) b0 |= (1u << pos);
          if (acc[1][ct][r] >= t1) b1 |= (1u << pos);
        }
      } else {
#pragma unroll
        for (int r = 0; r < 16; ++r) {
          int pos = (r & 3) + 8 * (r >> 2) + 4 * half;
          bool ok = (c0 + pos >= s) && (c0 + pos < e);
          if (ok && acc[0][ct][r] >= t0) b0 |= (1u << pos);
          if (ok && acc[1][ct][r] >= t1) b1 |= (1u << pos);
        }
      }
      b0 |= __shfl_xor(b0, 32, 64);
      b1 |= __shfl_xor(b1, 32, 64);
      unsigned m = half ? b1 : b0;             // own token's bits
      while (m) {
        int j = __ffs(m) - 1;
        m &= m - 1;
        if (cnt < SLOTS) cl[tid][cnt] = (unsigned short)(c0 + j);
        ++cnt;
      }
    }
    __syncthreads();                           // Cs writes visible before next compute
  }
  // ---- final record write: 32 B per token, coalesced ----
  int token = tb * TTOK + tid;
  const unsigned* clu = (const unsigned*)cl[tid];
  uint4 w0, w1;
  w0.x = (unsigned)cnt; w0.y = clu[0]; w0.z = clu[1]; w0.w = clu[2];
  w1.x = clu[3]; w1.y = clu[4]; w1.z = clu[5]; w1.w = clu[6];
  unsigned* rec = cand + ((size_t)cbk * NTOK + token) * 8;
  *(uint4*)rec = w0;
  *(uint4*)(rec + 4) = w1;
}

// ---------------- pass 2: record-driven exact rescue + epilogue ----------------------
// Wave per token. Lane = (block=lane>>4, slot=lane&15): one parallel eval round
// covers all candidates. Overflow blocks (cnt>14): exact full-block scan.
__global__ __launch_bounds__(256) void vq_rescue(
    const float* __restrict__ x, const float* __restrict__ cb,
    const float* __restrict__ sc, const unsigned int* __restrict__ cand,
    float* __restrict__ out_xq, float* __restrict__ out_idx,
    float* __restrict__ partial,
    const int* __restrict__ p_start, const int* __restrict__ p_end) {
#pragma clang fp contract(off)
  __shared__ float xs[4][64];
  __shared__ float sdata[4];
  int tid  = threadIdx.x;
  int wv   = tid >> 6;
  int lane = tid & 63;
  int token = blockIdx.x * 4 + wv;

  float xx = x[(size_t)token * EDIM + lane];
  xs[wv][lane] = xx;
  __syncthreads();
  const float4* xl4 = (const float4*)xs[wv];

  // sx = np.sum(x*x) pairwise-8 replica
  float a[8];
#pragma unroll
  for (int j = 0; j < 8; ++j) a[j] = 0.0f;
#pragma unroll
  for (int i = 0; i < 8; ++i) {
    float4 pA = xl4[2*i], pB = xl4[2*i+1];
    a[0] += pA.x * pA.x; a[1] += pA.y * pA.y; a[2] += pA.z * pA.z; a[3] += pA.w * pA.w;
    a[4] += pB.x * pB.x; a[5] += pB.y * pB.y; a[6] += pB.z * pB.z; a[7] += pB.w * pB.w;
  }
  float sx = ((a[0]+a[1]) + (a[2]+a[3])) + ((a[4]+a[5]) + (a[6]+a[7]));

  int s = *p_start, e = *p_end;
  unsigned long long bestpack = ~0ull;

  int b = lane >> 4, slot = lane & 15;
  const unsigned* rec = cand + ((size_t)b * NTOK + token) * 8;
  unsigned cnt = rec[0];
  if (cnt <= SLOTS && slot < (int)cnt) {
    int k = (int)((rec[1 + (slot >> 1)] >> ((slot & 1) * 16)) & 0xFFFFu);
    unsigned long long pk = vq_eval_pack(cb, k, xl4, sx, sc);
    if (pk < bestpack) bestpack = pk;
  }
  // overflow blocks: exact cooperative scan (rare)
  unsigned long long ovf = __ballot(slot == 0 && cnt > SLOTS);
  while (ovf) {
    int ob = (__ffsll((long long)ovf) - 1) >> 4;
    ovf &= ovf - 1;
#pragma unroll 1
    for (int r = 0; r < TCODE / 64; ++r) {
      int k = ob * TCODE + r * 64 + lane;
      if (k >= s && k < e) {
        unsigned long long pk = vq_eval_pack(cb, k, xl4, sx, sc);
        if (pk < bestpack) bestpack = pk;
      }
    }
  }
  // lex-min reduce: (d asc, k asc) == numpy first-occurrence argmin
#pragma unroll
  for (int off = 32; off >= 1; off >>= 1) {
    unsigned long long o = __shfl_xor(bestpack, off, 64);
    if (o < bestpack) bestpack = o;
  }
  int bidx = (int)(unsigned int)(bestpack & 0xFFFFFFFFull);

  float qv = cb[(size_t)bidx * EDIM + lane];
  float diff = qv - xx;                              // fl(x_q - x)
  out_xq[(size_t)token * EDIM + lane] = xx + diff;   // fl(x + fl(x_q - x))
  if (lane == 0) out_idx[token] = (float)bidx;

  float l = diff * diff;
#pragma unroll
  for (int off = 32; off >= 1; off >>= 1) l += __shfl_down(l, off, 64);
  if (lane == 0) sdata[wv] = l;
  __syncthreads();
  if (tid == 0)
    partial[blockIdx.x] = (sdata[0] + sdata[1]) + (sdata[2] + sdata[3]);
}

// ---------------- final loss reduction ----------------------------------------------
__global__ __launch_bounds__(256) void vq_loss(const float* __restrict__ partial,
                                               float* __restrict__ out_loss) {
  int tid = threadIdx.x;
  float s = 0.0f;
  for (int i = tid; i < NTOK / 4; i += 256) s += partial[i];
#pragma unroll
  for (int off = 32; off >= 1; off >>= 1) s += __shfl_down(s, off, 64);
  __shared__ float sdata[4];
  if ((tid & 63) == 0) sdata[tid >> 6] = s;
  __syncthreads();
  if (tid == 0) {
    float total = (sdata[0] + sdata[1]) + (sdata[2] + sdata[3]);
    float m = total * (1.0f / (float)NELEM);
    out_loss[0] = m + 0.25f * m;
  }
}

// ---------------- launch -------------------------------------------------------------
extern "C" void kernel_launch(void* const* d_in, const int* in_sizes, int n_in,
                              void* d_out, int out_size, void* d_ws, size_t ws_size,
                              hipStream_t stream) {
  const float* x  = (const float*)d_in[0];
  const float* cb = (const float*)d_in[1];
  const int* p_start = (const int*)d_in[2];
  const int* p_end   = (const int*)d_in[3];

  float* ws = (float*)d_ws;
  float* sc      = ws;                                            // 8192 f
  float* partial = ws + N_E;                                      // 8192 f
  unsigned short* cbf = (unsigned short*)(ws + 2 * N_E);          // 8192*80 us (1.3MB)
  unsigned int*   cand = (unsigned int*)(cbf + (size_t)N_E * KEXT); // 4*32768*8 u32 (4MB)

  float* out      = (float*)d_out;
  float* out_xq   = out;                 // 2097152
  float* out_loss = out + NELEM;         // 1
  float* out_idx  = out + NELEM + 1;     // 32768

  vq_sc<<<N_E / 256, 256, 0, stream>>>(cb, sc, cbf);
  dim3 g1(NTOK / TTOK, N_E / TCODE);
  vq_pass1<<<g1, 256, 0, stream>>>(x, cbf, cand, p_start, p_end);
  vq_rescue<<<NTOK / 4, 256, 0, stream>>>(x, cb, sc, cand, out_xq, out_idx,
                                          partial, p_start, p_end);
  vq_loss<<<1, 256, 0, stream>>>(partial, out_loss);
}

// Round 11
// 218.957 us; speedup vs baseline: 3.2574x; 3.2574x over previous
//
#include <hip/hip_runtime.h>
#include <math.h>

// VectorQuantizer: x (32768,64) f32, codebook (8192,64) f32, start/end/use_sk ints.
// Outputs concat: x_q_st (2097152 f32) | loss (1 f32) | indices (32768 as f32 values).
//
// R11: bf16-MFMA filter -> per-(token, 32-code chunk) f16 minima (kept in registers,
// flushed as coalesced 32B stores every 4 iterations); rescue re-evaluates ALL codes
// of flagged chunks (~2.5/token) straight from global cb with the BIT-EXACT R1
// numpy-replica arithmetic. No masks, no records, no overflow path (R10's flaw:
// running-max append threshold was too loose early -> frequent overflow full scans).
//  vq_sc:   sc_k exact (pairwise-8 numpy replica, f32) + cb -> cbf_ext rows
//           [c0..c63, bf16(sc_k), 0*15] (K padded 64->80; sc folded via x-ext -0.5).
//  vq_pass1: 32x32x16 MFMA, block = 256 tokens x 2048 codes (16 iters of 128).
//           Per iter: per-chunk max in acc space -> g=-2*max -> f16 pair-packed into
//           rolling regs; every 4 iters one 32B store (2x uint4) at 512B lane stride
//           (block's 128KB row-set is L2-resident -> lines fill -> no write amp).
//  vq_rescue: wave/token. Coalesced 512B minima row, butterfly min -> thr, ballots ->
//           flagged chunks; chunks popped in PAIRS (half-wave each, lane=code), codes
//           evaluated from global cb with the BIT-EXACT R1 arithmetic (pairwise-8,
//           separate mul+add); lex-min (enc(d),k) == strict-< ascending-k.
// Correctness: flagged-chunk filter (f16 minima, W=3e-4) is exactly the R5-R9
// validated criterion (bf16 dot err + f16 store + ref d-slop ~1.9e-4 < W); rescuing
// every code of flagged chunks is a superset of R9's mask-selected candidates.
// DO NOT change the exact-path arithmetic: inter-code d gaps are ~1 ulp of d.

#define N_E    8192
#define EDIM   64
#define NTOK   32768
#define NELEM  (NTOK * EDIM)
#define CSZ    32                  // chunk size
#define NCHUNK (N_E / CSZ)         // 256 chunks
#define WINDOW 3e-4f
#define KEXT   80                  // padded K (64 data + sc-fold + zeros)
#define TTOK   256                 // pass-1 tokens per block
#define TCODE  2048                // pass-1 codes per block (16 iters of 128)
#define SROW   88                  // LDS row stride (ushorts; 44 dwords == 4 mod 8)

typedef __attribute__((ext_vector_type(8)))  short          short8;
typedef __attribute__((ext_vector_type(8)))  unsigned short ushort8v;
typedef __attribute__((ext_vector_type(4)))  unsigned short ushort4v;
typedef __attribute__((ext_vector_type(16))) float          f32x16;

__device__ __forceinline__ unsigned short f2bf(float f) {   // RTNE f32->bf16 bits
  unsigned int u = __float_as_uint(f);
  return (unsigned short)((u + 0x7FFFu + ((u >> 16) & 1u)) >> 16);
}
__device__ __forceinline__ unsigned short f2h(float f) {
  union { _Float16 h; unsigned short u; } cv; cv.h = (_Float16)f; return cv.u;
}
__device__ __forceinline__ float h2f(unsigned short b) {
  union { _Float16 h; unsigned short u; } cv; cv.u = b; return (float)cv.h;
}

// BIT-EXACT R1 numpy-replica distance eval (validated absmax 0.0 since R1).
// DO NOT reorder: products rounded separately, 8 stride-8 accumulators,
// combine ((t0+t1)+(t2+t3))+((t4+t5)+(t6+t7)), d = fl(fl(sx+sc)-2*tt).
__device__ __forceinline__ unsigned long long vq_eval_pack(
    const float* __restrict__ cb, int k, const float4* __restrict__ xl4,
    float sx, const float* __restrict__ sc) {
#pragma clang fp contract(off)
  const float4* c4 = (const float4*)(cb + (size_t)k * EDIM);
  float t[8];
#pragma unroll
  for (int j = 0; j < 8; ++j) t[j] = 0.0f;
#pragma unroll
  for (int i = 0; i < 8; ++i) {              // elements 8i..8i+7, i ascending
    float4 cA4 = c4[2*i], cB4 = c4[2*i+1];
    float4 pA = xl4[2*i], pB = xl4[2*i+1];
    t[0] += cA4.x * pA.x; t[1] += cA4.y * pA.y;
    t[2] += cA4.z * pA.z; t[3] += cA4.w * pA.w;
    t[4] += cB4.x * pB.x; t[5] += cB4.y * pB.y;
    t[6] += cB4.z * pB.z; t[7] += cB4.w * pB.w;
  }
  float tt = ((t[0]+t[1]) + (t[2]+t[3])) + ((t[4]+t[5]) + (t[6]+t[7]));
  float d = (sx + sc[k]) - 2.0f * tt;
  unsigned int db = __float_as_uint(d);
  unsigned int en = db ^ ((unsigned int)((int)db >> 31) | 0x80000000u);
  return ((unsigned long long)en << 32) | (unsigned int)k;
}

// ---------------- sc (exact pairwise-8) + cb -> bf16 ext rows [c, sc, zeros] ---------
__global__ __launch_bounds__(256) void vq_sc(const float* __restrict__ cb,
                                             float* __restrict__ sc,
                                             unsigned short* __restrict__ cbf) {
#pragma clang fp contract(off)
  int r = blockIdx.x * 256 + threadIdx.x;
  const float4* c4 = (const float4*)(cb + (size_t)r * EDIM);
  float a[8];
#pragma unroll
  for (int j = 0; j < 8; ++j) a[j] = 0.0f;
#pragma unroll
  for (int i = 0; i < 8; ++i) {
    float4 pA = c4[2*i], pB = c4[2*i+1];
    a[0] += pA.x * pA.x; a[1] += pA.y * pA.y; a[2] += pA.z * pA.z; a[3] += pA.w * pA.w;
    a[4] += pB.x * pB.x; a[5] += pB.y * pB.y; a[6] += pB.z * pB.z; a[7] += pB.w * pB.w;
  }
  float sval = ((a[0]+a[1]) + (a[2]+a[3])) + ((a[4]+a[5]) + (a[6]+a[7]));
  sc[r] = sval;
  unsigned short* dst = cbf + (size_t)r * KEXT;
#pragma unroll
  for (int h = 0; h < 8; ++h) {
    float4 fA = c4[2*h], fB = c4[2*h+1];
    ushort8v o = {f2bf(fA.x), f2bf(fA.y), f2bf(fA.z), f2bf(fA.w),
                  f2bf(fB.x), f2bf(fB.y), f2bf(fB.z), f2bf(fB.w)};
    *(ushort8v*)&dst[h * 8] = o;
  }
  ushort8v t0 = {0,0,0,0,0,0,0,0};
  t0[0] = f2bf(sval);
  *(ushort8v*)&dst[64] = t0;
  ushort8v z = {0,0,0,0,0,0,0,0};
  *(ushort8v*)&dst[72] = z;
}

// ---------------- pass 1: 32x32x16 MFMA filter -> per-chunk f16 minima ---------------
// Frags: A[m=lane&31][k=8*(lane>>5)+j] (codes), B same (tokens),
// D: col=lane&31 (token), row=(reg&3)+8*(reg>>2)+4*(lane>>5) (code).
__global__ __launch_bounds__(256, 2) void vq_pass1(
    const float* __restrict__ x, const unsigned short* __restrict__ cbf,
    unsigned short* __restrict__ minima,
    const int* __restrict__ p_start, const int* __restrict__ p_end) {
  __shared__ unsigned short Xs[TTOK * SROW];   // 45056 B
  __shared__ unsigned short Cs[128 * SROW];    // 22528 B
  int tid = threadIdx.x;
  int tb = blockIdx.x;    // token split [0,128)
  int cbk = blockIdx.y;   // code split  [0,4)
  int s = *p_start, e = *p_end;

  // ---- stage x tile (fused f32 -> bf16-ext conversion) ----
  const float4* xg = (const float4*)(x + (size_t)tb * TTOK * EDIM);
#pragma unroll
  for (int p = 0; p < 16; ++p) {
    int idx = tid + p * 256;                   // [0,4096): row*16 + c4
    int row = idx >> 4, c4i = idx & 15;
    float4 f = xg[idx];
    ushort4v o = {f2bf(f.x), f2bf(f.y), f2bf(f.z), f2bf(f.w)};
    *(ushort4v*)&Xs[row * SROW + c4i * 4] = o;
  }
  {                                            // tail cols 64..79: [-0.5, zeros]
    ushort8v t0 = {0,0,0,0,0,0,0,0};
    t0[0] = f2bf(-0.5f);
    ushort8v z = {0,0,0,0,0,0,0,0};
    *(ushort8v*)&Xs[tid * SROW + 64] = t0;
    *(ushort8v*)&Xs[tid * SROW + 72] = z;
  }
  // ---- stage first code tile: 128 rows x 10 ushort8 = 1280 ----
  const ushort8v* cg0 = (const ushort8v*)(cbf + (size_t)cbk * TCODE * KEXT);
#pragma unroll
  for (int p = 0; p < 5; ++p) {
    int idx = tid + p * 256;
    int row = idx / 10, h = idx % 10;
    *(ushort8v*)&Cs[row * SROW + h * 8] = cg0[idx];
  }
  __syncthreads();

  int lane = tid & 63, wv = tid >> 6;
  int half = lane >> 5, ln = lane & 31;
  int tokbase = wv * 64;
  short8 bfr[2][5];
#pragma unroll
  for (int tg = 0; tg < 2; ++tg)
#pragma unroll
    for (int ks = 0; ks < 5; ++ks)
      bfr[tg][ks] = *(const short8*)&Xs[(tokbase + tg*32 + ln) * SROW + ks*16 + half*8];

  int token = tb * TTOK + tokbase + lane;      // lane's own token
  unsigned short* rowp = minima + (size_t)token * NCHUNK + cbk * 64;

  for (int nbg = 0; nbg < 4; ++nbg) {          // 4 groups of 4 iterations
    unsigned pk8[8];                           // rolling 16 chunk-f16 (32 B)
#pragma unroll
    for (int ni = 0; ni < 4; ++ni) {
      int nb = nbg * 4 + ni;
      ushort8v creg[5];
      if (nb < 15) {
        const ushort8v* cg =
            (const ushort8v*)(cbf + ((size_t)cbk * TCODE + (nb + 1) * 128) * KEXT);
#pragma unroll
        for (int p = 0; p < 5; ++p) creg[p] = cg[tid + p * 256];
      }
      f32x16 acc[2][4];
#pragma unroll
      for (int tg = 0; tg < 2; ++tg)
#pragma unroll
        for (int ct = 0; ct < 4; ++ct) acc[tg][ct] = (f32x16)0.0f;
#pragma unroll
      for (int ks = 0; ks < 5; ++ks)
#pragma unroll
        for (int ct = 0; ct < 4; ++ct) {
          short8 a = *(const short8*)&Cs[(ct*32 + ln) * SROW + ks*16 + half*8];
          acc[0][ct] = __builtin_amdgcn_mfma_f32_32x32x16_bf16(a, bfr[0][ks],
                                                               acc[0][ct], 0, 0, 0);
          acc[1][ct] = __builtin_amdgcn_mfma_f32_32x32x16_bf16(a, bfr[1][ks],
                                                               acc[1][ct], 0, 0, 0);
        }
      __syncthreads();                         // all Cs reads done
      if (nb < 15) {
#pragma unroll
        for (int p = 0; p < 5; ++p) {
          int idx = tid + p * 256;
          int row = idx / 10, h = idx % 10;
          *(ushort8v*)&Cs[row * SROW + h * 8] = creg[p];
        }
      }
      // ---- epilogue (registers only; overlaps LDS writes): per-chunk minima ----
      int cbase0 = cbk * TCODE + nb * 128;
      bool full = (cbase0 >= s) && (cbase0 + 128 <= e);
      float cm[4];                             // own token's 4 chunk g-minima
#pragma unroll
      for (int ct = 0; ct < 4; ++ct) {
        float v0 = -INFINITY, v1 = -INFINITY;
        if (full) {
#pragma unroll
          for (int r = 0; r < 16; ++r) {
            v0 = fmaxf(v0, acc[0][ct][r]);
            v1 = fmaxf(v1, acc[1][ct][r]);
          }
        } else {
          int c0 = cbase0 + ct * 32;
#pragma unroll
          for (int r = 0; r < 16; ++r) {
            int code = c0 + (r & 3) + 8 * (r >> 2) + 4 * half;
            if (code >= s && code < e) {
              v0 = fmaxf(v0, acc[0][ct][r]);
              v1 = fmaxf(v1, acc[1][ct][r]);
            }
          }
        }
        v0 = fmaxf(v0, __shfl_xor(v0, 32, 64));
        v1 = fmaxf(v1, __shfl_xor(v1, 32, 64));
        cm[ct] = half ? v1 : v0;
      }
      pk8[ni*2]     = (unsigned)f2h(-2.0f * cm[0])
                    | ((unsigned)f2h(-2.0f * cm[1]) << 16);
      pk8[ni*2 + 1] = (unsigned)f2h(-2.0f * cm[2])
                    | ((unsigned)f2h(-2.0f * cm[3]) << 16);
      __syncthreads();                         // Cs writes visible before next compute
    }
    // ---- flush 16 chunk minima (32 B) for this lane's token ----
    uint4 w0, w1;
    w0.x = pk8[0]; w0.y = pk8[1]; w0.z = pk8[2]; w0.w = pk8[3];
    w1.x = pk8[4]; w1.y = pk8[5]; w1.z = pk8[6]; w1.w = pk8[7];
    *(uint4*)(rowp + nbg * 16)     = w0;
    *(uint4*)(rowp + nbg * 16 + 8) = w1;
  }
}

// ---------------- pass 2: flagged-chunk exact rescue + epilogue ----------------------
// Wave per token. Flagged chunks popped in pairs (half-wave each, lane=code),
// evaluated from global cb with the BIT-EXACT R1 arithmetic.
__global__ __launch_bounds__(256) void vq_rescue(
    const float* __restrict__ x, const float* __restrict__ cb,
    const float* __restrict__ sc, const unsigned short* __restrict__ minima,
    float* __restrict__ out_xq, float* __restrict__ out_idx,
    float* __restrict__ partial,
    const int* __restrict__ p_start, const int* __restrict__ p_end) {
#pragma clang fp contract(off)
  __shared__ float xs[4][64];
  __shared__ float sdata[4];
  int tid  = threadIdx.x;
  int wv   = tid >> 6;
  int lane = tid & 63;
  int token = blockIdx.x * 4 + wv;

  float xx = x[(size_t)token * EDIM + lane];
  xs[wv][lane] = xx;
  __syncthreads();
  const float4* xl4 = (const float4*)xs[wv];

  // sx = np.sum(x*x) pairwise-8 replica
  float a[8];
#pragma unroll
  for (int j = 0; j < 8; ++j) a[j] = 0.0f;
#pragma unroll
  for (int i = 0; i < 8; ++i) {
    float4 pA = xl4[2*i], pB = xl4[2*i+1];
    a[0] += pA.x * pA.x; a[1] += pA.y * pA.y; a[2] += pA.z * pA.z; a[3] += pA.w * pA.w;
    a[4] += pB.x * pB.x; a[5] += pB.y * pB.y; a[6] += pB.z * pB.z; a[7] += pB.w * pB.w;
  }
  float sx = ((a[0]+a[1]) + (a[2]+a[3])) + ((a[4]+a[5]) + (a[6]+a[7]));

  // minima row: lane covers chunks 4*lane .. 4*lane+3 (coalesced uint2, 512B/wave)
  uint2 u2 = *(const uint2*)(minima + (size_t)token * NCHUNK + lane * 4);
  float mv[4] = {h2f((unsigned short)(u2.x & 0xFFFFu)),
                 h2f((unsigned short)(u2.x >> 16)),
                 h2f((unsigned short)(u2.y & 0xFFFFu)),
                 h2f((unsigned short)(u2.y >> 16))};
  float m = fminf(fminf(mv[0], mv[1]), fminf(mv[2], mv[3]));
#pragma unroll
  for (int off = 32; off >= 1; off >>= 1) m = fminf(m, __shfl_xor(m, off, 64));
  float thr = m + WINDOW;
  unsigned long long fmask[4];
#pragma unroll
  for (int cc = 0; cc < 4; ++cc) fmask[cc] = __ballot(mv[cc] <= thr);

  int s = *p_start, e = *p_end;
  unsigned long long bestpack = ~0ull;
  int half = lane >> 5;
  int pend = -1;

#pragma unroll 1
  for (int cc = 0; cc < 5; ++cc) {             // cc==4: flush pending
    unsigned long long fm = (cc < 4) ? fmask[cc] : 0ull;
    while (fm || (cc == 4 && pend >= 0)) {
      int cA, cB;
      if (cc == 4) { cA = pend; cB = -1; pend = -2; }
      else {
        int b = __ffsll((long long)fm) - 1; fm &= fm - 1;
        int c = b * 4 + cc;
        if (pend < 0) { pend = c; continue; }
        cA = pend; cB = c; pend = -1;
      }
      int ch = half ? cB : cA;
      if (ch >= 0) {
        int k = ch * CSZ + (lane & 31);
        if (k >= s && k < e) {
          unsigned long long pk = vq_eval_pack(cb, k, xl4, sx, sc);
          if (pk < bestpack) bestpack = pk;
        }
      }
      if (pend == -2) { pend = -1; break; }
    }
  }
  // lex-min reduce: (d asc, k asc) == numpy first-occurrence argmin
#pragma unroll
  for (int off = 32; off >= 1; off >>= 1) {
    unsigned long long o = __shfl_xor(bestpack, off, 64);
    if (o < bestpack) bestpack = o;
  }
  int bidx = (int)(unsigned int)(bestpack & 0xFFFFFFFFull);

  float qv = cb[(size_t)bidx * EDIM + lane];
  float diff = qv - xx;                              // fl(x_q - x)
  out_xq[(size_t)token * EDIM + lane] = xx + diff;   // fl(x + fl(x_q - x))
  if (lane == 0) out_idx[token] = (float)bidx;

  float l = diff * diff;
#pragma unroll
  for (int off = 32; off >= 1; off >>= 1) l += __shfl_down(l, off, 64);
  if (lane == 0) sdata[wv] = l;
  __syncthreads();
  if (tid == 0)
    partial[blockIdx.x] = (sdata[0] + sdata[1]) + (sdata[2] + sdata[3]);
}

// ---------------- final loss reduction ----------------------------------------------
__global__ __launch_bounds__(256) void vq_loss(const float* __restrict__ partial,
                                               float* __restrict__ out_loss) {
  int tid = threadIdx.x;
  float s = 0.0f;
  for (int i = tid; i < NTOK / 4; i += 256) s += partial[i];
#pragma unroll
  for (int off = 32; off >= 1; off >>= 1) s += __shfl_down(s, off, 64);
  __shared__ float sdata[4];
  if ((tid & 63) == 0) sdata[tid >> 6] = s;
  __syncthreads();
  if (tid == 0) {
    float total = (sdata[0] + sdata[1]) + (sdata[2] + sdata[3]);
    float m = total * (1.0f / (float)NELEM);
    out_loss[0] = m + 0.25f * m;
  }
}

// ---------------- launch -------------------------------------------------------------
extern "C" void kernel_launch(void* const* d_in, const int* in_sizes, int n_in,
                              void* d_out, int out_size, void* d_ws, size_t ws_size,
                              hipStream_t stream) {
  const float* x  = (const float*)d_in[0];
  const float* cb = (const float*)d_in[1];
  const int* p_start = (const int*)d_in[2];
  const int* p_end   = (const int*)d_in[3];

  float* ws = (float*)d_ws;
  float* sc      = ws;                                            // 8192 f
  float* partial = ws + N_E;                                      // 8192 f
  unsigned short* cbf = (unsigned short*)(ws + 2 * N_E);          // 8192*80 us (1.3MB)
  unsigned short* minima = cbf + (size_t)N_E * KEXT;              // 32768*256 us (16MB)

  float* out      = (float*)d_out;
  float* out_xq   = out;                 // 2097152
  float* out_loss = out + NELEM;         // 1
  float* out_idx  = out + NELEM + 1;     // 32768

  vq_sc<<<N_E / 256, 256, 0, stream>>>(cb, sc, cbf);
  dim3 g1(NTOK / TTOK, N_E / TCODE);
  vq_pass1<<<g1, 256, 0, stream>>>(x, cbf, minima, p_start, p_end);
  vq_rescue<<<NTOK / 4, 256, 0, stream>>>(x, cb, sc, minima, out_xq, out_idx,
                                          partial, p_start, p_end);
  vq_loss<<<1, 256, 0, stream>>>(partial, out_loss);
}